// Round 9
// baseline (574.700 us; speedup 1.0000x reference)
//
#include <hip/hip_runtime.h>

// RNN_73813307949430: 4x LSTM(H=50,T=10,F=5) + Dense(50) + Dense(1,sigmoid), B=131072.
// Round 12: R10 gate math (plain-rcp — measured fastest: short independent dep
// chains beat shared-rcp's serial mul tree) + latency-hiding schedule:
//  (1) h-reads issued FIRST post-barrier; x-MFMAs run from prefetched regs while
//      h0/h1 fly (~120cy LDS latency hidden under 8 MFMAs instead of exposed to
//      all 4 lockstep waves);
//  (2) x-frags of step t+1 prefetched before the gate phase (reads bufX[t+1], or
//      bufW[0] at the layer seam — both written many barriers ago, barrier-safe),
//      in flight under ~300cy of gate VALU.
// Structure: layer-parity double buffer buf[2][T][1024], 1 barrier/step, MTILE=16,
// 4 waves, launch_bounds(256,4), LDS 40960 B, bias-as-MFMA-C.
// Tripwire: WRITE_SIZE <= ~6 MB (arch file at the 64-reg cap; +8 prefetch regs).
//
// LDS buf half per t (1024 u16 = 2 KB): chunk(kk,quad) at u16 offset
// (kk*4+quad)*128+rr*8 holds h[row=rr][unit=kk*32+quad*8+j]. MFMA A-frag:
// lane(np,quad) reads 16B at kk*512+quad*128+np*8 -> conflict-free.
// Weights Wpp: k 0..63 = X/h^{l-1}, k 64..127 = recurrent, prescaled by +-log2e.

typedef __attribute__((ext_vector_type(8))) short short8;
typedef __attribute__((ext_vector_type(4))) float floatx4;
typedef __attribute__((ext_vector_type(2))) float float2v;
typedef unsigned short u16;
typedef unsigned int u32;

constexpr int H_ = 50, T_ = 10, F_ = 5;
constexpr int MTILE = 16;   // batch rows per block
constexpr int BLKT = 256;   // 4 waves
constexpr float LOG2E = 1.4426950408889634f;

__device__ __forceinline__ float rcp_(float x) { return __builtin_amdgcn_rcpf(x); }
__device__ __forceinline__ float exp2_(float x) { return __builtin_amdgcn_exp2f(x); }
__device__ __forceinline__ float sig_nat(float x) {
  return rcp_(1.0f + exp2_(-LOG2E * x));
}

__device__ __forceinline__ u16 f2bf(float f) {
  union { float f; unsigned u; } v; v.f = f;
  unsigned r = v.u + 0x7FFFu + ((v.u >> 16) & 1u);  // RNE
  return (u16)(r >> 16);
}
__device__ __forceinline__ float bf2f(u16 s) {
  union { unsigned u; float f; } v; v.u = ((unsigned)s) << 16;
  return v.f;
}
// gfx950 packed f32->bf16 RNE convert (no builtin; inline asm). lo->bits[15:0].
__device__ __forceinline__ unsigned cvt_pk_bf16(float lo, float hi) {
  unsigned r;
  asm("v_cvt_pk_bf16_f32 %0, %1, %2" : "=v"(r) : "v"(lo), "v"(hi));
  return r;
}

// ---- prep: swizzle weights into B-fragment order with activation prescale ----
// Wpp[layer][kt][gate][wave][lane][8]; B[k=(lane>>4)*8+j][n=lane&15].
// Gates i,f,o scaled by -log2e (sig = rcp(1+exp2(z))); gate g by +2*log2e
// (tanh = 1-2*rcp(1+exp2(z))). Bias scaled identically.
__global__ void prep_kernel(
    const float* W1, const float* U1, const float* b1, const float* W2,
    const float* U2, const float* b2, const float* W3, const float* U3,
    const float* b3, const float* W4, const float* U4, const float* b4,
    const float* Wd1, const float* bd1, const float* Wd2, const float* bd2,
    u16* Wpp, float* biasP, float* vdense) {
  int idx = blockIdx.x * blockDim.x + threadIdx.x;
  const float* Wt[4] = {W1, W2, W3, W4};
  const float* Ut[4] = {U1, U2, U3, U4};
  const float* bt[4] = {b1, b2, b3, b4};
  const int fin[4] = {F_, H_, H_, H_};
  if (idx < 4 * 32768) {
    int l = idx >> 15, r = idx & 32767;
    int j = r & 7, lane = (r >> 3) & 63, w = (r >> 9) & 3, gI = (r >> 11) & 3,
        kt = r >> 13;
    int row = kt * 32 + (lane >> 4) * 8 + j;  // K position (0..127)
    int u = w * 16 + (lane & 15);             // unit (0..63)
    float val = 0.0f;
    if (u < H_) {
      if (row < 64) {
        if (row < fin[l]) val = Wt[l][row * 200 + gI * H_ + u];
      } else {
        int rr = row - 64;
        if (rr < H_) val = Ut[l][rr * 200 + gI * H_ + u];
      }
    }
    val *= (gI == 2) ? (2.0f * LOG2E) : (-LOG2E);
    Wpp[idx] = f2bf(val);
  } else if (idx < 4 * 32768 + 1024) {
    int r = idx - 4 * 32768;
    int l = r >> 8, q = r & 255, gI = q >> 6, u = q & 63;
    float val = (u < H_) ? bt[l][gI * H_ + u] : 0.0f;
    biasP[r] = val * ((gI == 2) ? (2.0f * LOG2E) : (-LOG2E));
  } else if (idx < 4 * 32768 + 1024 + 51) {
    int u = idx - (4 * 32768 + 1024);
    if (u < H_) {  // v = Wd1 @ Wd2 (Dense(50) linear -> collapse)
      float s = 0.0f;
      for (int n = 0; n < H_; ++n) s += Wd1[u * H_ + n] * Wd2[n];
      vdense[u] = s;
    } else {
      float s = bd2[0];
      for (int n = 0; n < H_; ++n) s += bd1[n] * Wd2[n];
      vdense[50] = s;
    }
  }
}

// ---- fully fused 4-layer LSTM + dense head ----
__global__ __launch_bounds__(BLKT, 4) void lstm_fused(
    const float* __restrict__ x0, const u16* __restrict__ Wpp,
    const float* __restrict__ biasP, const float* __restrict__ vdense,
    float* __restrict__ out) {
  // Two parity buffers. buf[0] starts as x (layer-0 input); each layer writes its
  // h into the opposite-parity buffer: l0: 0->1, l1: 1->0, l2: 0->1, l3: 1->0.
  __shared__ __align__(16) u16 buf[2][T_ * 1024];  // 40960 B = 160KiB/4 exactly

  const int tid = threadIdx.x;
  const int w = tid >> 6, lane = tid & 63;
  const int np = lane & 15, quad = lane >> 4;
  const int b0 = blockIdx.x * MTILE;
  const int u = w * 16 + np;

  // zero-fill both buffers (pad k-slots and garbage-unit slots must be finite
  // zeros: zero weights * NaN = NaN would poison the MFMA)
  for (int i = tid; i < 2 * T_ * 512; i += BLKT) ((u32*)buf)[i] = 0;
  __syncthreads();
  // stage ALL timesteps of layer-1 input into buf[0][t] fragment slots (k=f, 0..4)
  for (int e = tid; e < MTILE * 50; e += BLKT) {
    int row = e / 50, q = e - row * 50;
    int t = q / 5, f = q - t * 5;
    buf[0][t * 1024 + row * 8 + f] = f2bf(x0[(size_t)(b0 + row) * 50 + q]);
  }
  __syncthreads();

  // A-frag read base: chunk(kk,quad,rr=np) -> kk*512 + quad*128 + np*8
  const int rbase = quad * 128 + np * 8;
  // h-write base: unit u -> kk=u>>5=w>>1, qk=((w&1)*2+(np>>3)), j=np&7; rows quad*4+2p
  const int cb0 = (w >> 1) * 512 + ((w & 1) * 2 + (np >> 3)) * 128 + quad * 32 + (np & 7);

  float2v cst[2];  // c state pairs: [p], rows quad*4+{2p,2p+1}, unit u

  // X fragments for the CURRENT step, prefetched one step ahead.
  short8 xa0 = *(const short8*)&buf[0][rbase];  // l=0,t=0: x, kt=0 only
  short8 xa1 = xa0;                             // defined (unused for l=0)

#pragma unroll 1
  for (int l = 0; l < 4; ++l) {
    // per-layer weight fragments from L2 (prescaled), 64 regs (AGPR-resident)
    const u16* wp = Wpp + l * 32768;
    short8 bfr[4][4];
#pragma unroll
    for (int kt = 0; kt < 4; ++kt)
#pragma unroll
      for (int g = 0; g < 4; ++g)
        bfr[kt][g] = *(const short8*)&wp[(((kt * 4 + g) * 4 + w) * 64 + lane) * 8];
    // bias fragments: built once per layer, used as the C operand of each gate's
    // first MFMA every step (D != C, so bias4 is never clobbered).
    floatx4 bias4[4];
#pragma unroll
    for (int g = 0; g < 4; ++g) {
      float bv = biasP[l * 256 + g * 64 + u];
      bias4[g] = floatx4{bv, bv, bv, bv};
    }
    cst[0] = float2v{0.0f, 0.0f};
    cst[1] = float2v{0.0f, 0.0f};

    const u16* bufX = buf[l & 1];        // X source: x (l=0) or h^{l-1}
    u16* bufW = buf[(l & 1) ^ 1];        // write target; also H source (own h)

#pragma unroll 1
    for (int t = 0; t < T_; ++t) {
      // ---- 1. issue h-reads FIRST (post-barrier); they fly under x-MFMAs ----
      short8 h0, h1;
      if (t > 0) {
        const u16* bp = bufW + (t - 1) * 1024;
        h0 = *(const short8*)&bp[rbase];
        h1 = *(const short8*)&bp[512 + rbase];
      }

      // ---- 2. x-MFMAs from prefetched regs (no LDS wait) ----
      floatx4 acc[4];
#pragma unroll
      for (int g = 0; g < 4; ++g)
        acc[g] = __builtin_amdgcn_mfma_f32_16x16x32_bf16(xa0, bfr[0][g],
                                                         bias4[g], 0, 0, 0);
      if (l > 0) {
#pragma unroll
        for (int g = 0; g < 4; ++g)
          acc[g] = __builtin_amdgcn_mfma_f32_16x16x32_bf16(xa1, bfr[1][g],
                                                           acc[g], 0, 0, 0);
      }

      // ---- 3. prefetch next step's x-frags (fly under h-MFMAs + gate VALU) ----
      // t<9: bufX[t+1] (stable: written last layer / prologue). t==9, l<3:
      // bufW[0] = h^l_0, the NEXT layer's X at t=0 (final since step 0, many
      // barriers ago). Next layer is l+1>=1 -> needs both halves.
      if (t < T_ - 1) {
        const u16* ns = bufX + (t + 1) * 1024;
        xa0 = *(const short8*)&ns[rbase];
        if (l > 0) xa1 = *(const short8*)&ns[512 + rbase];
      } else if (l < 3) {
        xa0 = *(const short8*)&bufW[rbase];
        xa1 = *(const short8*)&bufW[512 + rbase];
      }

      // ---- 4. recurrent h-MFMAs (h0/h1 landed during step 2) ----
      if (t > 0) {
#pragma unroll
        for (int g = 0; g < 4; ++g) {
          acc[g] = __builtin_amdgcn_mfma_f32_16x16x32_bf16(h0, bfr[2][g], acc[g],
                                                           0, 0, 0);
          acc[g] = __builtin_amdgcn_mfma_f32_16x16x32_bf16(h1, bfr[3][g], acc[g],
                                                           0, 0, 0);
        }
      }

      // Reads this step: bufX[t+1 or next-layer 0], bufW[t-1]; writes: bufW[t]
      // -> all disjoint, no pre-gate barrier needed.

      // ---- 5. gates: plain-rcp form (R10 — measured fastest) ----
      u16* bw = bufW + t * 1024;
#pragma unroll
      for (int p = 0; p < 2; ++p) {
        float2v di = {exp2_(acc[0][2 * p]), exp2_(acc[0][2 * p + 1])};
        float2v df = {exp2_(acc[1][2 * p]), exp2_(acc[1][2 * p + 1])};
        float2v dg = {exp2_(acc[2][2 * p]), exp2_(acc[2][2 * p + 1])};
        float2v do_ = {exp2_(acc[3][2 * p]), exp2_(acc[3][2 * p + 1])};
        di += 1.0f; df += 1.0f; dg += 1.0f; do_ += 1.0f;
        float2v i_ = {rcp_(di.x), rcp_(di.y)};      // sigmoid(zi)
        float2v f_ = {rcp_(df.x), rcp_(df.y)};      // sigmoid(zf)
        float2v o_ = {rcp_(do_.x), rcp_(do_.y)};    // sigmoid(zo)
        float2v rg = {rcp_(dg.x), rcp_(dg.y)};
        float2v g_ = 1.0f - 2.0f * rg;              // tanh(zg)
        float2v cn = f_ * cst[p] + i_ * g_;
        cst[p] = cn;
        float2v s = cn * (2.0f * LOG2E);
        float2v dc = {exp2_(s.x), exp2_(s.y)};
        dc += 1.0f;
        float2v rc = {rcp_(dc.x), rcp_(dc.y)};
        float2v tc = 1.0f - 2.0f * rc;              // tanh(cn)
        float2v h = o_ * tc;
        unsigned pk = cvt_pk_bf16(h.x, h.y);
        int a0w = cb0 + p * 16;
        bw[a0w] = (u16)pk;
        bw[a0w + 8] = (u16)(pk >> 16);
      }
      __syncthreads();  // publish h^l_t for next step's H read / next layer's X
    }
  }

  // ---- dense head: out = sigmoid(h^4_9 . (Wd1@Wd2) + beta) ----
  // layer 3 writes parity 0: h^4 lives in buf[0].
  if (tid < MTILE) {
    int rr = tid;
    const u16* b9 = &buf[0][9 * 1024];
    float s = vdense[50];
    for (int k = 0; k < H_; ++k) {
      int kk = k >> 5, qd = (k & 31) >> 3, j = k & 7;
      s += bf2f(b9[kk * 512 + qd * 128 + rr * 8 + j]) * vdense[k];
    }
    out[b0 + tid] = sig_nat(s);
  }
}

extern "C" void kernel_launch(void* const* d_in, const int* in_sizes, int n_in,
                              void* d_out, int out_size, void* d_ws,
                              size_t ws_size, hipStream_t stream) {
  const float* x = (const float*)d_in[0];
  const float* W1 = (const float*)d_in[1];
  const float* U1 = (const float*)d_in[2];
  const float* b1 = (const float*)d_in[3];
  const float* W2 = (const float*)d_in[4];
  const float* U2 = (const float*)d_in[5];
  const float* b2 = (const float*)d_in[6];
  const float* W3 = (const float*)d_in[7];
  const float* U3 = (const float*)d_in[8];
  const float* b3 = (const float*)d_in[9];
  const float* W4 = (const float*)d_in[10];
  const float* U4 = (const float*)d_in[11];
  const float* b4 = (const float*)d_in[12];
  const float* Wd1 = (const float*)d_in[13];
  const float* bd1 = (const float*)d_in[14];
  const float* Wd2 = (const float*)d_in[15];
  const float* bd2 = (const float*)d_in[16];

  const int Bn = in_sizes[0] / (T_ * F_);  // 131072
  const int nblk = Bn / MTILE;             // 8192
  char* ws = (char*)d_ws;
  u16* Wpp = (u16*)ws;                          // 4 x 32768 bf16 = 256 KB
  float* biasP = (float*)(ws + 262144);         // 4 x 256 f32
  float* vdense = (float*)(ws + 262144 + 4096); // 51 f32
  float* out = (float*)d_out;

  prep_kernel<<<(4 * 32768 + 1024 + 51 + 255) / 256, 256, 0, stream>>>(
      W1, U1, b1, W2, U2, b2, W3, U3, b3, W4, U4, b4, Wd1, bd1, Wd2, bd2, Wpp,
      biasP, vdense);

  lstm_fused<<<dim3(nblk), dim3(BLKT), 0, stream>>>(x, Wpp, biasP, vdense, out);
}

// Round 10
// 476.804 us; speedup vs baseline: 1.2053x; 1.2053x over previous
//
#include <hip/hip_runtime.h>

// RNN_73813307949430: 4x LSTM(H=50,T=10,F=5) + Dense(50) + Dense(1,sigmoid), B=131072.
// Round 13: REVERT to R10 — the measured optimum. R12's prefetch schedule spilled
// (+8 live regs across the gate phase -> WRITE_SIZE 3.6MB->287MB, 559us). Plateau
// map from R9-R12: occupancy capped by 64-arch + 64-AGPR weight block (R5/R8/R12:
// any reg added spills; any forced cap spills); gate VALU is at the per-element
// transcendental floor (20 exp2 + 20 rcp per thread-step); issue-slot variants are
// +-0.5% (R9/R10/R11). R10 config: bias-as-MFMA-C (no acc-init movs), plain-rcp
// gates (short independent dep chains beat shared-rcp's serial mul tree), layer-
// parity double buffer, 1 barrier/step, MTILE=16, 4 waves, launch_bounds(256,4),
// LDS 40960 B, 4 blocks/CU, zero spill. Steady-state 445.6 us measured.
//
// LDS buf half per t (1024 u16 = 2 KB): chunk(kk,quad) at u16 offset
// (kk*4+quad)*128+rr*8 holds h[row=rr][unit=kk*32+quad*8+j]. MFMA A-frag:
// lane(np,quad) reads 16B at kk*512+quad*128+np*8 -> conflict-free.
// Weights Wpp: k 0..63 = X/h^{l-1}, k 64..127 = recurrent, prescaled by +-log2e.

typedef __attribute__((ext_vector_type(8))) short short8;
typedef __attribute__((ext_vector_type(4))) float floatx4;
typedef __attribute__((ext_vector_type(2))) float float2v;
typedef unsigned short u16;
typedef unsigned int u32;

constexpr int H_ = 50, T_ = 10, F_ = 5;
constexpr int MTILE = 16;   // batch rows per block
constexpr int BLKT = 256;   // 4 waves
constexpr float LOG2E = 1.4426950408889634f;

__device__ __forceinline__ float rcp_(float x) { return __builtin_amdgcn_rcpf(x); }
__device__ __forceinline__ float exp2_(float x) { return __builtin_amdgcn_exp2f(x); }
__device__ __forceinline__ float sig_nat(float x) {
  return rcp_(1.0f + exp2_(-LOG2E * x));
}

__device__ __forceinline__ u16 f2bf(float f) {
  union { float f; unsigned u; } v; v.f = f;
  unsigned r = v.u + 0x7FFFu + ((v.u >> 16) & 1u);  // RNE
  return (u16)(r >> 16);
}
__device__ __forceinline__ float bf2f(u16 s) {
  union { unsigned u; float f; } v; v.u = ((unsigned)s) << 16;
  return v.f;
}
// gfx950 packed f32->bf16 RNE convert (no builtin; inline asm). lo->bits[15:0].
__device__ __forceinline__ unsigned cvt_pk_bf16(float lo, float hi) {
  unsigned r;
  asm("v_cvt_pk_bf16_f32 %0, %1, %2" : "=v"(r) : "v"(lo), "v"(hi));
  return r;
}

// ---- prep: swizzle weights into B-fragment order with activation prescale ----
// Wpp[layer][kt][gate][wave][lane][8]; B[k=(lane>>4)*8+j][n=lane&15].
// Gates i,f,o scaled by -log2e (sig = rcp(1+exp2(z))); gate g by +2*log2e
// (tanh = 1-2*rcp(1+exp2(z))). Bias scaled identically.
__global__ void prep_kernel(
    const float* W1, const float* U1, const float* b1, const float* W2,
    const float* U2, const float* b2, const float* W3, const float* U3,
    const float* b3, const float* W4, const float* U4, const float* b4,
    const float* Wd1, const float* bd1, const float* Wd2, const float* bd2,
    u16* Wpp, float* biasP, float* vdense) {
  int idx = blockIdx.x * blockDim.x + threadIdx.x;
  const float* Wt[4] = {W1, W2, W3, W4};
  const float* Ut[4] = {U1, U2, U3, U4};
  const float* bt[4] = {b1, b2, b3, b4};
  const int fin[4] = {F_, H_, H_, H_};
  if (idx < 4 * 32768) {
    int l = idx >> 15, r = idx & 32767;
    int j = r & 7, lane = (r >> 3) & 63, w = (r >> 9) & 3, gI = (r >> 11) & 3,
        kt = r >> 13;
    int row = kt * 32 + (lane >> 4) * 8 + j;  // K position (0..127)
    int u = w * 16 + (lane & 15);             // unit (0..63)
    float val = 0.0f;
    if (u < H_) {
      if (row < 64) {
        if (row < fin[l]) val = Wt[l][row * 200 + gI * H_ + u];
      } else {
        int rr = row - 64;
        if (rr < H_) val = Ut[l][rr * 200 + gI * H_ + u];
      }
    }
    val *= (gI == 2) ? (2.0f * LOG2E) : (-LOG2E);
    Wpp[idx] = f2bf(val);
  } else if (idx < 4 * 32768 + 1024) {
    int r = idx - 4 * 32768;
    int l = r >> 8, q = r & 255, gI = q >> 6, u = q & 63;
    float val = (u < H_) ? bt[l][gI * H_ + u] : 0.0f;
    biasP[r] = val * ((gI == 2) ? (2.0f * LOG2E) : (-LOG2E));
  } else if (idx < 4 * 32768 + 1024 + 51) {
    int u = idx - (4 * 32768 + 1024);
    if (u < H_) {  // v = Wd1 @ Wd2 (Dense(50) linear -> collapse)
      float s = 0.0f;
      for (int n = 0; n < H_; ++n) s += Wd1[u * H_ + n] * Wd2[n];
      vdense[u] = s;
    } else {
      float s = bd2[0];
      for (int n = 0; n < H_; ++n) s += bd1[n] * Wd2[n];
      vdense[50] = s;
    }
  }
}

// ---- fully fused 4-layer LSTM + dense head ----
__global__ __launch_bounds__(BLKT, 4) void lstm_fused(
    const float* __restrict__ x0, const u16* __restrict__ Wpp,
    const float* __restrict__ biasP, const float* __restrict__ vdense,
    float* __restrict__ out) {
  // Two parity buffers. buf[0] starts as x (layer-0 input); each layer writes its
  // h into the opposite-parity buffer: l0: 0->1, l1: 1->0, l2: 0->1, l3: 1->0.
  __shared__ __align__(16) u16 buf[2][T_ * 1024];  // 40960 B = 160KiB/4 exactly

  const int tid = threadIdx.x;
  const int w = tid >> 6, lane = tid & 63;
  const int np = lane & 15, quad = lane >> 4;
  const int b0 = blockIdx.x * MTILE;
  const int u = w * 16 + np;

  // zero-fill both buffers (pad k-slots and garbage-unit slots must be finite
  // zeros: zero weights * NaN = NaN would poison the MFMA)
  for (int i = tid; i < 2 * T_ * 512; i += BLKT) ((u32*)buf)[i] = 0;
  __syncthreads();
  // stage ALL timesteps of layer-1 input into buf[0][t] fragment slots (k=f, 0..4)
  for (int e = tid; e < MTILE * 50; e += BLKT) {
    int row = e / 50, q = e - row * 50;
    int t = q / 5, f = q - t * 5;
    buf[0][t * 1024 + row * 8 + f] = f2bf(x0[(size_t)(b0 + row) * 50 + q]);
  }
  __syncthreads();

  // A-frag read base: chunk(kk,quad,rr=np) -> kk*512 + quad*128 + np*8
  const int rbase = quad * 128 + np * 8;
  // h-write base: unit u -> kk=u>>5=w>>1, qk=((w&1)*2+(np>>3)), j=np&7; rows quad*4+2p
  const int cb0 = (w >> 1) * 512 + ((w & 1) * 2 + (np >> 3)) * 128 + quad * 32 + (np & 7);

  float2v cst[2];  // c state pairs: [p], rows quad*4+{2p,2p+1}, unit u

#pragma unroll 1
  for (int l = 0; l < 4; ++l) {
    // per-layer weight fragments from L2 (prescaled), 64 regs (AGPR-resident)
    const u16* wp = Wpp + l * 32768;
    short8 bfr[4][4];
#pragma unroll
    for (int kt = 0; kt < 4; ++kt)
#pragma unroll
      for (int g = 0; g < 4; ++g)
        bfr[kt][g] = *(const short8*)&wp[(((kt * 4 + g) * 4 + w) * 64 + lane) * 8];
    // bias fragments: built once per layer, used as the C operand of each gate's
    // first MFMA every step (D != C, so bias4 is never clobbered).
    floatx4 bias4[4];
#pragma unroll
    for (int g = 0; g < 4; ++g) {
      float bv = biasP[l * 256 + g * 64 + u];
      bias4[g] = floatx4{bv, bv, bv, bv};
    }
    cst[0] = float2v{0.0f, 0.0f};
    cst[1] = float2v{0.0f, 0.0f};

    const u16* bufX = buf[l & 1];        // X source: x (l=0) or h^{l-1}
    u16* bufW = buf[(l & 1) ^ 1];        // write target; also H source (own h)

#pragma unroll 1
    for (int t = 0; t < T_; ++t) {
      floatx4 acc[4];

      // X-half MFMA (l=0: k=5..63 weights zero -> kt=0 only). First MFMA per
      // gate consumes bias4[g] as C — no acc init movs.
      const u16* bx = bufX + t * 1024;
      short8 a0 = *(const short8*)&bx[rbase];
#pragma unroll
      for (int g = 0; g < 4; ++g)
        acc[g] = __builtin_amdgcn_mfma_f32_16x16x32_bf16(a0, bfr[0][g],
                                                         bias4[g], 0, 0, 0);
      if (l > 0) {
        short8 a1 = *(const short8*)&bx[512 + rbase];
#pragma unroll
        for (int g = 0; g < 4; ++g)
          acc[g] = __builtin_amdgcn_mfma_f32_16x16x32_bf16(a1, bfr[1][g],
                                                           acc[g], 0, 0, 0);
      }
      if (t > 0) {  // recurrent H = own h_{t-1} in bufW[t-1]; h_{-1}=0 -> skip
        const u16* bp = bufW + (t - 1) * 1024;
        short8 h0 = *(const short8*)&bp[rbase];
        short8 h1 = *(const short8*)&bp[512 + rbase];
#pragma unroll
        for (int g = 0; g < 4; ++g) {
          acc[g] = __builtin_amdgcn_mfma_f32_16x16x32_bf16(h0, bfr[2][g], acc[g],
                                                           0, 0, 0);
          acc[g] = __builtin_amdgcn_mfma_f32_16x16x32_bf16(h1, bfr[3][g], acc[g],
                                                           0, 0, 0);
        }
      }

      // All reads this step touched bufX[t] and bufW[t-1]; writes go to bufW[t]
      // -> disjoint, no pre-gate barrier needed.

      // ---- gates: plain-rcp form (prescaled z: i,f,o by -log2e; g by 2log2e) ----
      u16* bw = bufW + t * 1024;
#pragma unroll
      for (int p = 0; p < 2; ++p) {
        float2v di = {exp2_(acc[0][2 * p]), exp2_(acc[0][2 * p + 1])};
        float2v df = {exp2_(acc[1][2 * p]), exp2_(acc[1][2 * p + 1])};
        float2v dg = {exp2_(acc[2][2 * p]), exp2_(acc[2][2 * p + 1])};
        float2v do_ = {exp2_(acc[3][2 * p]), exp2_(acc[3][2 * p + 1])};
        di += 1.0f; df += 1.0f; dg += 1.0f; do_ += 1.0f;
        float2v i_ = {rcp_(di.x), rcp_(di.y)};      // sigmoid(zi)
        float2v f_ = {rcp_(df.x), rcp_(df.y)};      // sigmoid(zf)
        float2v o_ = {rcp_(do_.x), rcp_(do_.y)};    // sigmoid(zo)
        float2v rg = {rcp_(dg.x), rcp_(dg.y)};
        float2v g_ = 1.0f - 2.0f * rg;              // tanh(zg)
        float2v cn = f_ * cst[p] + i_ * g_;
        cst[p] = cn;
        float2v s = cn * (2.0f * LOG2E);
        float2v dc = {exp2_(s.x), exp2_(s.y)};
        dc += 1.0f;
        float2v rc = {rcp_(dc.x), rcp_(dc.y)};
        float2v tc = 1.0f - 2.0f * rc;              // tanh(cn)
        float2v h = o_ * tc;
        unsigned pk = cvt_pk_bf16(h.x, h.y);
        int a0w = cb0 + p * 16;
        bw[a0w] = (u16)pk;
        bw[a0w + 8] = (u16)(pk >> 16);
      }
      __syncthreads();  // publish h^l_t for next step's H read / next layer's X
    }
  }

  // ---- dense head: out = sigmoid(h^4_9 . (Wd1@Wd2) + beta) ----
  // layer 3 writes parity 0: h^4 lives in buf[0].
  if (tid < MTILE) {
    int rr = tid;
    const u16* b9 = &buf[0][9 * 1024];
    float s = vdense[50];
    for (int k = 0; k < H_; ++k) {
      int kk = k >> 5, qd = (k & 31) >> 3, j = k & 7;
      s += bf2f(b9[kk * 512 + qd * 128 + rr * 8 + j]) * vdense[k];
    }
    out[b0 + tid] = sig_nat(s);
  }
}

extern "C" void kernel_launch(void* const* d_in, const int* in_sizes, int n_in,
                              void* d_out, int out_size, void* d_ws,
                              size_t ws_size, hipStream_t stream) {
  const float* x = (const float*)d_in[0];
  const float* W1 = (const float*)d_in[1];
  const float* U1 = (const float*)d_in[2];
  const float* b1 = (const float*)d_in[3];
  const float* W2 = (const float*)d_in[4];
  const float* U2 = (const float*)d_in[5];
  const float* b2 = (const float*)d_in[6];
  const float* W3 = (const float*)d_in[7];
  const float* U3 = (const float*)d_in[8];
  const float* b3 = (const float*)d_in[9];
  const float* W4 = (const float*)d_in[10];
  const float* U4 = (const float*)d_in[11];
  const float* b4 = (const float*)d_in[12];
  const float* Wd1 = (const float*)d_in[13];
  const float* bd1 = (const float*)d_in[14];
  const float* Wd2 = (const float*)d_in[15];
  const float* bd2 = (const float*)d_in[16];

  const int Bn = in_sizes[0] / (T_ * F_);  // 131072
  const int nblk = Bn / MTILE;             // 8192
  char* ws = (char*)d_ws;
  u16* Wpp = (u16*)ws;                          // 4 x 32768 bf16 = 256 KB
  float* biasP = (float*)(ws + 262144);         // 4 x 256 f32
  float* vdense = (float*)(ws + 262144 + 4096); // 51 f32
  float* out = (float*)d_out;

  prep_kernel<<<(4 * 32768 + 1024 + 51 + 255) / 256, 256, 0, stream>>>(
      W1, U1, b1, W2, U2, b2, W3, U3, b3, W4, U4, b4, Wd1, bd1, Wd2, bd2, Wpp,
      biasP, vdense);

  lstm_fused<<<dim3(nblk), dim3(BLKT), 0, stream>>>(x, Wpp, biasP, vdense, out);
}